// Round 2
// baseline (213.786 us; speedup 1.0000x reference)
//
#include <hip/hip_runtime.h>
#include <hip/hip_bf16.h>

// Problem constants
#define N_TOK 8192
#define INL   512
#define OUTL  512
#define NE    8
#define NI    16
#define EOFF  (OUTL * INL)   // elems per expert in wt

typedef unsigned short ushort_t;
typedef unsigned int   uint_t;
typedef short  short8  __attribute__((ext_vector_type(8)));
typedef float  floatx4 __attribute__((ext_vector_type(4)));

// ---------------- workspace layout (bytes) ----------------
#define WS_CNT    0u         // int[16] @ stride 16 ints (64B): [slot*8+e]
#define WS_GAM    2048u      // float[8]   : gam[e]
#define WS_RGAM   2080u      // float[8]   : router_gamma[e]
#define WS_BET    2112u      // float[4096]: bet_eff[e][d] = bet + gam*b
#define WS_SELW   51264u     // float4[8192]: {rw0*gam0, rw1*gam1, rw0, rw1}
#define WS_WT     182336u    // ushort[8*512*512] : W^T bf16 [e][d][l]
#define WS_LIST   4380672u   // int[2*8*8192] : token lists per (slot, expert)
#define MAXT3     144        // worst-case sum over 16 lists of ceil(cnt/128)

__device__ __forceinline__ ushort_t f2bf(float f) {
    uint_t b = __float_as_uint(f);
    return (ushort_t)((b + 0x7FFFu + ((b >> 16) & 1u)) >> 16);   // RNE
}
__device__ __forceinline__ uint_t pkbf(float a, float b) {
    __hip_bfloat162 h = __float22bfloat162_rn(make_float2(a, b));  // v_cvt_pk_bf16_f32
    union { __hip_bfloat162 h2; uint_t u; } cv;
    cv.h2 = h;
    return cv.u;
}
// async global->LDS DMA, 16 B per lane; LDS dest = wave-uniform base + lane*16
__device__ __forceinline__ void dma16(const ushort_t* g, ushort_t* l) {
    __builtin_amdgcn_global_load_lds(
        (const __attribute__((address_space(1))) void*)g,
        (__attribute__((address_space(3))) void*)l,
        16, 0, 0);
}

// ================= K1: fused prep =================
// blocks [0,512):   Wt transpose/convert  (e = bx>>6; tile = bx&63)
// blocks [512,640): bet_eff               (e = b>>4; dBase = (b&15)*32)
// block  640:       stats -> wsGam, wsRgam; zero scatter counters
__global__ __launch_bounds__(256)
void k_prep(const float* __restrict__ ins,
            const float* __restrict__ expert_w,
            const float* __restrict__ expert_b,
            const float* __restrict__ gamma_w,
            const float* __restrict__ beta_w,
            const float* __restrict__ rmod_w,
            ushort_t* __restrict__ wt,
            float* __restrict__ wsBet,
            float* __restrict__ wsGam, float* __restrict__ wsRgam,
            int* __restrict__ wsCnt) {
    __shared__ __align__(16) char smem[17152];
    int bx = blockIdx.x;
    int tid = threadIdx.x;

    if (bx < 512) {
        float (*tile)[65] = (float(*)[65])smem;
        int e = bx >> 6, rem = bx & 63;
        int lt = (rem >> 3) * 64, dt = (rem & 7) * 64;
        int dIdx = tid & 63, lq = tid >> 6;
        for (int i = 0; i < 16; ++i) {
            int l = lq * 16 + i;
            tile[l][dIdx] = expert_w[(e * INL + lt + l) * OUTL + dt + dIdx];
        }
        __syncthreads();
        int lIdx = tid & 63, dq = tid >> 6;
        for (int i = 0; i < 16; ++i) {
            int d = dq * 16 + i;
            wt[(e * OUTL + dt + d) * INL + lt + lIdx] = f2bf(tile[lIdx][d]);
        }
        return;
    }

    if (bx < 640) {
        float* sS  = (float*)smem;          // [512]
        float* red = sS + 512;              // [256]
        float* gamS = red + 256;            // [1]
        int b2 = bx - 512;
        int e = b2 >> 4, dBase = (b2 & 15) * 32;
        for (int h = tid; h < INL; h += 256) {
            float a = 0.f;
            for (int n = 0; n < NI; ++n) a += ins[n * INL + h];
            sS[h] = a;
        }
        __syncthreads();
        if (tid < 64) {
            float g = 0.f;
            for (int j = 0; j < 8; ++j) g += sS[tid * 8 + j] * gamma_w[e * INL + tid * 8 + j];
            for (int off = 32; off >= 1; off >>= 1) g += __shfl_xor(g, off, 64);
            if (tid == 0) gamS[0] = g * (1.f / NI);
        }
        int doff = tid & 31, hq = tid >> 5;
        float a = 0.f;
        for (int j = 0; j < 64; ++j) {
            int h = hq * 64 + j;
            a += sS[h] * beta_w[(e * INL + h) * OUTL + dBase + doff];
        }
        red[tid] = a;
        __syncthreads();
        if (tid < 32) {
            float t = 0.f;
            for (int k = 0; k < 8; ++k) t += red[k * 32 + tid];
            int d = dBase + tid;
            wsBet[e * OUTL + d] = t * (1.f / NI) + gamS[0] * expert_b[e * OUTL + d];
        }
        return;
    }

    {   // stats
        if (tid < 16) wsCnt[tid * 16] = 0;   // zero scatter counters for k_route
        float* sS = (float*)smem;           // [512]
        float* pg = sS + 512;               // [64]
        float* pr = pg + 64;                // [64]
        for (int h = tid; h < INL; h += 256) {
            float a = 0.f;
            for (int n = 0; n < NI; ++n) a += ins[n * INL + h];
            sS[h] = a;
        }
        __syncthreads();
        if (tid < 64) {
            int e = tid & 7, qq = tid >> 3;
            float g = 0.f, r = 0.f;
            for (int j = 0; j < 64; ++j) {
                int h = qq * 64 + j;
                float sv = sS[h];
                g += sv * gamma_w[e * INL + h];
                r += sv * rmod_w[h * NE + e];
            }
            pg[tid] = g; pr[tid] = r;
        }
        __syncthreads();
        if (tid < NE) {
            float g = 0.f, r = 0.f;
            for (int qq = 0; qq < 8; ++qq) { g += pg[qq * 8 + tid]; r += pr[qq * 8 + tid]; }
            wsGam[tid]  = g * (1.f / NI);
            wsRgam[tid] = r * (1.f / NI);
        }
    }
}

// ================= K2: router + LDS-compacted scatter + beta-init ==========
// 128 tokens/block (grid 64). Per-block expert lists built with LDS atomics;
// ONE global atomicAdd per (slot,expert) per block (1024 total, was 16384).
// Also pre-writes out[t] = rw0*bet_eff[e0] + rw1*bet_eff[e1] (deterministic
// init; the gemm then only atomically accumulates the two GEMM terms).
__global__ __launch_bounds__(256)
void k_route(const float* __restrict__ x,
             const float* __restrict__ gate_w,
             const float* __restrict__ wsGam,
             const float* __restrict__ wsRgam,
             const float* __restrict__ wsBet,
             float4* __restrict__ selW,
             int* __restrict__ wsCnt, int* __restrict__ wsList,
             float* __restrict__ out) {
    __shared__ float gateT[NE * INL];   // 16 KB, [e][l]; reused for bet_eff
    __shared__ int   tokLE[128];        // e0 | e1<<8
    __shared__ float tokWz[128], tokWw[128];
    __shared__ int   cnt16[16], base16[16], pos0[128], pos1[128];

    int tid = threadIdx.x;
    for (int i = 0; i < 16; ++i) {
        int f = tid + 256 * i;
        gateT[(f & 7) * INL + (f >> 3)] = gate_w[f];
    }
    if (tid < 16) cnt16[tid] = 0;
    __syncthreads();

    int w = tid >> 6, lane = tid & 63;
    int tbase = blockIdx.x * 128 + w * 32;

    for (int tt = 0; tt < 32; ++tt) {
        int t = tbase + tt;
        float2 xv[4];
        for (int i = 0; i < 4; ++i)
            xv[i] = *(const float2*)(x + (size_t)t * INL + 2 * lane + 128 * i);

        float acc[NE];
        for (int e = 0; e < NE; ++e) acc[e] = 0.f;
        for (int i = 0; i < 4; ++i) {
            int c = 2 * lane + 128 * i;
            for (int e = 0; e < NE; ++e)
                acc[e] += xv[i].x * gateT[e * INL + c] + xv[i].y * gateT[e * INL + c + 1];
        }
        for (int e = 0; e < NE; ++e) {
            float a = acc[e];
            for (int off = 32; off >= 1; off >>= 1) a += __shfl_xor(a, off, 64);
            acc[e] = a;
        }
        float logit[NE];
        for (int e = 0; e < NE; ++e) logit[e] = acc[e] + wsRgam[e];

        int i0 = 0; float m0 = logit[0];
        for (int e = 1; e < NE; ++e) if (logit[e] > m0) { m0 = logit[e]; i0 = e; }
        int i1 = -1; float m1 = -3.4e38f;
        for (int e = 0; e < NE; ++e) if (e != i0 && logit[e] > m1) { m1 = logit[e]; i1 = e; }

        float S = 0.f;
        for (int e = 0; e < NE; ++e) S += expf(logit[e] - m0);
        float rw0 = 1.0f / S;
        float rw1 = expf(m1 - m0) / S;

        if (lane == 0) {
            int j = w * 32 + tt;
            tokLE[j] = i0 | (i1 << 8);
            tokWz[j] = rw0; tokWw[j] = rw1;
            selW[t] = make_float4(rw0 * wsGam[i0], rw1 * wsGam[i1], rw0, rw1);
        }
    }
    __syncthreads();

    // per-block compaction (LDS atomics), then one global atomic per list
    if (tid < 128) {
        int es = tokLE[tid];
        pos0[tid] = atomicAdd(&cnt16[es & 255], 1);
        pos1[tid] = atomicAdd(&cnt16[8 + (es >> 8)], 1);
    }
    __syncthreads();
    if (tid < 16) base16[tid] = atomicAdd(wsCnt + tid * 16, cnt16[tid]);
    __syncthreads();
    if (tid < 128) {
        int t = blockIdx.x * 128 + tid;
        int es = tokLE[tid];
        int e0 = es & 255, e1 = es >> 8;
        wsList[e0 * N_TOK + base16[e0] + pos0[tid]] = t;
        wsList[(8 + e1) * N_TOK + base16[8 + e1] + pos1[tid]] = t;
    }
    __syncthreads();

    // stage bet_eff over gateT, then write beta background rows
    for (int i = 0; i < 16; ++i) gateT[tid + 256 * i] = wsBet[tid + 256 * i];
    __syncthreads();
    for (int j = w; j < 128; j += 4) {
        int t = blockIdx.x * 128 + j;
        int es = tokLE[j];
        const float* b0 = gateT + (es & 255) * OUTL;
        const float* b1 = gateT + (es >> 8) * OUTL;
        float wz = tokWz[j], ww = tokWw[j];
        float* op = out + (size_t)t * OUTL;
        for (int h = 0; h < 2; ++h) {
            int c = lane * 4 + h * 256;
            float4 v0 = *(const float4*)(b0 + c);
            float4 v1 = *(const float4*)(b1 + c);
            float4 o;
            o.x = wz * v0.x + ww * v1.x;
            o.y = wz * v0.y + ww * v1.y;
            o.z = wz * v0.z + ww * v1.z;
            o.w = wz * v0.w + ww * v1.w;
            *(float4*)(op + c) = o;
        }
    }
}

// ================= K3: gather GEMM, single pass over all 16 lists ==========
// Tile M=128 x N=64 (2x the MFMA per ds_read of the M=64 version). K-loop is
// the proven r8 swizzle structure (0 LDS bank conflicts). Epilogue
// atomically accumulates onto the beta background written by k_route
// (exactly 2 float adds per output element -> <=1 ulp order noise).
__global__ __launch_bounds__(256, 4)
void k_gemm3(const float* __restrict__ x, const ushort_t* __restrict__ wt,
             const int* __restrict__ wsCnt, const int* __restrict__ wsList,
             const float4* __restrict__ selW, float* __restrict__ out) {
    int bx = blockIdx.x;
    int ct = bx & 7;                   // col slab: ct*64..+64
    int bt = bx >> 3;                  // global row-tile index

    // map bt -> (list li, local tile lt) via 16-entry prefix scan
    int li = -1, lt = 0, cntE = 0, run = 0;
    #pragma unroll
    for (int i = 0; i < 16; ++i) {
        int ci = wsCnt[i * 16];
        int ti = (ci + 127) >> 7;
        if (li < 0 && bt < run + ti) { li = i; lt = bt - run; cntE = ci; }
        run += ti;
    }
    if (li < 0) return;                // surplus block
    int slot = li >> 3, e = li & 7;
    const int* listE = wsList + li * N_TOK;

    __shared__ ushort_t Blds[2][64 * 64];   // 2 x 8 KB, swizzled [col][slot]

    int tid = threadIdx.x;
    int wid = tid >> 6, lane = tid & 63;
    int wm = wid * 32;                 // wave's 32-row slice (2 row-frags)
    int mrow = lane & 15, laneq = lane >> 4, q8 = laneq * 8, qr = laneq * 4;

    // gathered A rows + combine weight per row-frag
    const float* arowp[2];
    float wgt[2];
    #pragma unroll
    for (int rf = 0; rf < 2; ++rf) {
        int idx = lt * 128 + wm + rf * 16 + mrow;
        int tok = 0; float wv = 0.f;
        if (idx < cntE) {
            tok = listE[idx];
            float4 w4 = selW[tok];
            wv = slot ? w4.y : w4.x;   // rw*gam for this slot's expert
        }
        arowp[rf] = x + (size_t)tok * INL + q8;
        wgt[rf] = wv;
    }

    // B staging: thread stages chunks c0=tid, c1=tid+256 (chunk = 8 k, 16 B)
    // chunk c -> col=c>>3, kslot=c&7, src kgrp=(kslot-col)&7  (rotate swizzle)
    int c0 = tid, c1 = tid + 256;
    int col0 = c0 >> 3, kg0 = ((c0 & 7) - col0) & 7;
    int col1 = c1 >> 3, kg1 = ((c1 & 7) - col1) & 7;
    const ushort_t* pB0 = wt + (size_t)e * EOFF + (size_t)(ct * 64 + col0) * INL + kg0 * 8;
    const ushort_t* pB1 = wt + (size_t)e * EOFF + (size_t)(ct * 64 + col1) * INL + kg1 * 8;
    ushort_t* ldsW0 = &Blds[0][0] + (wid * 64) * 8;        // + buf*4096
    ushort_t* ldsW1 = &Blds[0][0] + (256 + wid * 64) * 8;

    // fragment read swizzle
    int fcol[4], frot0[4];
    for (int nt = 0; nt < 4; ++nt) {
        fcol[nt] = nt * 16 + mrow;
        frot0[nt] = (laneq + fcol[nt]) & 7;
    }

    floatx4 comb[2][4];
    #pragma unroll
    for (int rf = 0; rf < 2; ++rf)
        for (int nt = 0; nt < 4; ++nt) comb[rf][nt] = (floatx4){0.f, 0.f, 0.f, 0.f};

    // prologue: DMA tile kc=0 into buf0, drain
    dma16(pB0, ldsW0);
    dma16(pB1, ldsW1);
    __syncthreads();

    #pragma unroll 1
    for (int kc = 0; kc < 8; ++kc) {
        int buf = kc & 1;
        // issue DMA for next kc into the other buffer (flies under compute)
        if (kc < 7) {
            size_t off = (size_t)(kc + 1) * 64;
            int nb = buf ^ 1;
            dma16(pB0 + off, ldsW0 + nb * 4096);
            dma16(pB1 + off, ldsW1 + nb * 4096);
        }

        // A: load, scale, pack -> bf16 fragments
        union AF { uint4 u; short8 s; } af[2][2];
        #pragma unroll
        for (int rf = 0; rf < 2; ++rf) {
            float wv = wgt[rf];
            #pragma unroll
            for (int ks = 0; ks < 2; ++ks) {
                const float* p = arowp[rf] + kc * 64 + ks * 32;
                float4 a0 = *(const float4*)p;
                float4 a1 = *(const float4*)(p + 4);
                af[rf][ks].u.x = pkbf(a0.x * wv, a0.y * wv);
                af[rf][ks].u.y = pkbf(a0.z * wv, a0.w * wv);
                af[rf][ks].u.z = pkbf(a1.x * wv, a1.y * wv);
                af[rf][ks].u.w = pkbf(a1.z * wv, a1.w * wv);
            }
        }

        const ushort_t* B = &Blds[buf][0];
        short8 bf[4][2];
        #pragma unroll
        for (int nt = 0; nt < 4; ++nt) {
            int cb = fcol[nt] * 64;
            bf[nt][0] = *(const short8*)&B[cb + frot0[nt] * 8];
            bf[nt][1] = *(const short8*)&B[cb + ((frot0[nt] + 4) & 7) * 8];
        }
        #pragma unroll
        for (int ks = 0; ks < 2; ++ks)
            for (int rf = 0; rf < 2; ++rf)
                for (int nt = 0; nt < 4; ++nt)
                    comb[rf][nt] = __builtin_amdgcn_mfma_f32_16x16x32_bf16(
                        af[rf][ks].s, bf[nt][ks], comb[rf][nt], 0, 0, 0);
        __syncthreads();   // drain next-DMA (overlapped) + release buf readers
    }

    // epilogue: atomically accumulate onto beta background
    #pragma unroll
    for (int rf = 0; rf < 2; ++rf)
        for (int ri = 0; ri < 4; ++ri) {
            int idx2 = lt * 128 + wm + rf * 16 + qr + ri;
            if (idx2 >= cntE) continue;
            int tok2 = listE[idx2];
            float* op = out + (size_t)tok2 * OUTL + ct * 64;
            #pragma unroll
            for (int nt = 0; nt < 4; ++nt)
                atomicAdd(op + nt * 16 + mrow, comb[rf][nt][ri]);
        }
}

extern "C" void kernel_launch(void* const* d_in, const int* in_sizes, int n_in,
                              void* d_out, int out_size, void* d_ws, size_t ws_size,
                              hipStream_t stream) {
    const float* x        = (const float*)d_in[0];
    const float* ins      = (const float*)d_in[1];
    const float* gate_w   = (const float*)d_in[2];
    const float* expert_w = (const float*)d_in[3];
    const float* expert_b = (const float*)d_in[4];
    const float* gamma_w  = (const float*)d_in[5];
    const float* beta_w   = (const float*)d_in[6];
    const float* rmod_w   = (const float*)d_in[7];
    float* out = (float*)d_out;

    char* ws = (char*)d_ws;
    int*      wsCnt  = (int*)(ws + WS_CNT);
    float*    wsGam  = (float*)(ws + WS_GAM);
    float*    wsRgam = (float*)(ws + WS_RGAM);
    float*    wsBet  = (float*)(ws + WS_BET);
    float4*   selW   = (float4*)(ws + WS_SELW);
    ushort_t* wt     = (ushort_t*)(ws + WS_WT);
    int*      wsList = (int*)(ws + WS_LIST);

    k_prep<<<641, 256, 0, stream>>>(ins, expert_w, expert_b,
                                    gamma_w, beta_w, rmod_w,
                                    wt, wsBet, wsGam, wsRgam, wsCnt);
    k_route<<<N_TOK / 128, 256, 0, stream>>>(x, gate_w, wsGam, wsRgam, wsBet,
                                             selW, wsCnt, wsList, out);
    k_gemm3<<<MAXT3 * 8, 256, 0, stream>>>(x, wt, wsCnt, wsList, selW, out);
}

// Round 4
// 165.690 us; speedup vs baseline: 1.2903x; 1.2903x over previous
//
#include <hip/hip_runtime.h>
#include <hip/hip_bf16.h>

// Problem constants
#define N_TOK 8192
#define INL   512
#define OUTL  512
#define NE    8
#define NI    16
#define EOFF  (OUTL * INL)   // elems per expert in wt

typedef unsigned short ushort_t;
typedef unsigned int   uint_t;
typedef short  short8  __attribute__((ext_vector_type(8)));
typedef float  floatx4 __attribute__((ext_vector_type(4)));

// ---------------- workspace layout (bytes) ----------------
#define WS_CNT    0u         // int[64] @ stride 16 ints (64B): pair = e0*8+e1
#define WS_GAM    4096u      // float[8]   : gam[e]
#define WS_RGAM   4352u      // float[8]   : router_gamma[e]
#define WS_BET    8192u      // float[4096]: bet_eff[e][d] = bet + gam*b
#define WS_SELW   32768u     // float4[8192]: {rw0*gam0, rw1*gam1, rw0, rw1}
#define WS_WT     163840u    // ushort[8*512*512] : W^T bf16 [e][d][l]
#define WS_LIST   4358144u   // int[64*8192] : token lists per pair
#define MAXTP     184        // bound: 56 pairs + 8192/64 tiles

__device__ __forceinline__ ushort_t f2bf(float f) {
    uint_t b = __float_as_uint(f);
    return (ushort_t)((b + 0x7FFFu + ((b >> 16) & 1u)) >> 16);   // RNE
}
__device__ __forceinline__ uint_t pkbf(float a, float b) {
    __hip_bfloat162 h = __float22bfloat162_rn(make_float2(a, b));  // v_cvt_pk_bf16_f32
    union { __hip_bfloat162 h2; uint_t u; } cv;
    cv.h2 = h;
    return cv.u;
}
// async global->LDS DMA, 16 B per lane; LDS dest = wave-uniform base + lane*16
__device__ __forceinline__ void dma16(const ushort_t* g, ushort_t* l) {
    __builtin_amdgcn_global_load_lds(
        (const __attribute__((address_space(1))) void*)g,
        (__attribute__((address_space(3))) void*)l,
        16, 0, 0);
}

// ================= K1: fused prep =================
// blocks [0,512):   Wt transpose/convert  (e = bx>>6; tile = bx&63)
// blocks [512,640): bet_eff               (e = b>>4; dBase = (b&15)*32)
// block  640:       stats -> wsGam, wsRgam; zero pair counters
__global__ __launch_bounds__(256)
void k_prep(const float* __restrict__ ins,
            const float* __restrict__ expert_w,
            const float* __restrict__ expert_b,
            const float* __restrict__ gamma_w,
            const float* __restrict__ beta_w,
            const float* __restrict__ rmod_w,
            ushort_t* __restrict__ wt,
            float* __restrict__ wsBet,
            float* __restrict__ wsGam, float* __restrict__ wsRgam,
            int* __restrict__ wsCnt) {
    __shared__ __align__(16) char smem[17152];
    int bx = blockIdx.x;
    int tid = threadIdx.x;

    if (bx < 512) {
        float (*tile)[65] = (float(*)[65])smem;
        int e = bx >> 6, rem = bx & 63;
        int lt = (rem >> 3) * 64, dt = (rem & 7) * 64;
        int dIdx = tid & 63, lq = tid >> 6;
        for (int i = 0; i < 16; ++i) {
            int l = lq * 16 + i;
            tile[l][dIdx] = expert_w[(e * INL + lt + l) * OUTL + dt + dIdx];
        }
        __syncthreads();
        int lIdx = tid & 63, dq = tid >> 6;
        for (int i = 0; i < 16; ++i) {
            int d = dq * 16 + i;
            wt[(e * OUTL + dt + d) * INL + lt + lIdx] = f2bf(tile[lIdx][d]);
        }
        return;
    }

    if (bx < 640) {
        float* sS  = (float*)smem;          // [512]
        float* red = sS + 512;              // [256]
        float* gamS = red + 256;            // [1]
        int b2 = bx - 512;
        int e = b2 >> 4, dBase = (b2 & 15) * 32;
        for (int h = tid; h < INL; h += 256) {
            float a = 0.f;
            for (int n = 0; n < NI; ++n) a += ins[n * INL + h];
            sS[h] = a;
        }
        __syncthreads();
        if (tid < 64) {
            float g = 0.f;
            for (int j = 0; j < 8; ++j) g += sS[tid * 8 + j] * gamma_w[e * INL + tid * 8 + j];
            for (int off = 32; off >= 1; off >>= 1) g += __shfl_xor(g, off, 64);
            if (tid == 0) gamS[0] = g * (1.f / NI);
        }
        int doff = tid & 31, hq = tid >> 5;
        float a = 0.f;
        for (int j = 0; j < 64; ++j) {
            int h = hq * 64 + j;
            a += sS[h] * beta_w[(e * INL + h) * OUTL + dBase + doff];
        }
        red[tid] = a;
        __syncthreads();
        if (tid < 32) {
            float t = 0.f;
            for (int k = 0; k < 8; ++k) t += red[k * 32 + tid];
            int d = dBase + tid;
            wsBet[e * OUTL + d] = t * (1.f / NI) + gamS[0] * expert_b[e * OUTL + d];
        }
        return;
    }

    {   // stats
        if (tid < 64) wsCnt[tid * 16] = 0;   // zero pair counters for k_route
        float* sS = (float*)smem;           // [512]
        float* pg = sS + 512;               // [64]
        float* pr = pg + 64;                // [64]
        for (int h = tid; h < INL; h += 256) {
            float a = 0.f;
            for (int n = 0; n < NI; ++n) a += ins[n * INL + h];
            sS[h] = a;
        }
        __syncthreads();
        if (tid < 64) {
            int e = tid & 7, qq = tid >> 3;
            float g = 0.f, r = 0.f;
            for (int j = 0; j < 64; ++j) {
                int h = qq * 64 + j;
                float sv = sS[h];
                g += sv * gamma_w[e * INL + h];
                r += sv * rmod_w[h * NE + e];
            }
            pg[tid] = g; pr[tid] = r;
        }
        __syncthreads();
        if (tid < NE) {
            float g = 0.f, r = 0.f;
            for (int qq = 0; qq < 8; ++qq) { g += pg[qq * 8 + tid]; r += pr[qq * 8 + tid]; }
            wsGam[tid]  = g * (1.f / NI);
            wsRgam[tid] = r * (1.f / NI);
        }
    }
}

// ================= K2: router + pair scatter (512 blocks, 16 tok/block) ====
// Routing math = round-0 proven structure (high occupancy, 4 serial tok/wave).
// Scatter: 64-bin LDS pair histogram, <=16 global atomicAdds per block onto
// 64B-padded counters, then compacted list writes. No out writes here.
__global__ __launch_bounds__(256)
void k_route(const float* __restrict__ x,
             const float* __restrict__ gate_w,
             const float* __restrict__ wsGam,
             const float* __restrict__ wsRgam,
             float4* __restrict__ selW,
             int* __restrict__ wsCnt, int* __restrict__ wsList) {
    __shared__ float gateT[NE * INL];   // 16 KB, [e][l]
    __shared__ int tokP[16];
    __shared__ int cnt64[64], base64[64], pos[16];

    int tid = threadIdx.x;
    for (int i = 0; i < 16; ++i) {
        int f = tid + 256 * i;
        gateT[(f & 7) * INL + (f >> 3)] = gate_w[f];
    }
    if (tid < 64) cnt64[tid] = 0;
    __syncthreads();

    int w = tid >> 6, lane = tid & 63;
    int tbase = blockIdx.x * 16 + w * 4;

    for (int tt = 0; tt < 4; ++tt) {
        int t = tbase + tt;
        float2 xv[4];
        for (int i = 0; i < 4; ++i)
            xv[i] = *(const float2*)(x + (size_t)t * INL + 2 * lane + 128 * i);

        float acc[NE];
        for (int e = 0; e < NE; ++e) acc[e] = 0.f;
        for (int i = 0; i < 4; ++i) {
            int c = 2 * lane + 128 * i;
            for (int e = 0; e < NE; ++e)
                acc[e] += xv[i].x * gateT[e * INL + c] + xv[i].y * gateT[e * INL + c + 1];
        }
        for (int e = 0; e < NE; ++e) {
            float a = acc[e];
            for (int off = 32; off >= 1; off >>= 1) a += __shfl_xor(a, off, 64);
            acc[e] = a;
        }
        float logit[NE];
        for (int e = 0; e < NE; ++e) logit[e] = acc[e] + wsRgam[e];

        int i0 = 0; float m0 = logit[0];
        for (int e = 1; e < NE; ++e) if (logit[e] > m0) { m0 = logit[e]; i0 = e; }
        int i1 = -1; float m1 = -3.4e38f;
        for (int e = 0; e < NE; ++e) if (e != i0 && logit[e] > m1) { m1 = logit[e]; i1 = e; }

        float S = 0.f;
        for (int e = 0; e < NE; ++e) S += expf(logit[e] - m0);
        float rw0 = 1.0f / S;
        float rw1 = expf(m1 - m0) / S;

        if (lane == 0) {
            selW[t] = make_float4(rw0 * wsGam[i0], rw1 * wsGam[i1], rw0, rw1);
            tokP[w * 4 + tt] = i0 * 8 + i1;
        }
    }
    __syncthreads();

    if (tid < 16) pos[tid] = atomicAdd(&cnt64[tokP[tid]], 1);
    __syncthreads();
    if (tid < 64 && cnt64[tid] > 0)
        base64[tid] = atomicAdd(wsCnt + tid * 16, cnt64[tid]);
    __syncthreads();
    if (tid < 16) {
        int p = tokP[tid];
        wsList[(size_t)p * N_TOK + base64[p] + pos[tid]] = blockIdx.x * 16 + tid;
    }
}

// ================= K3: pair-gather GEMM, single pass, no atomics ===========
// Block owns (pair (e0,e1), 64-token tile, 64-col slab). Stages BOTH expert
// panels (proven r8 swizzle per panel), accumulates w0*x*W_e0 + w1*x*W_e1
// into one accumulator, epilogue writes the COMPLETE output segment
// (+ rw0*bet_eff[e0] + rw1*bet_eff[e1]) with a plain store. Deterministic.
__global__ __launch_bounds__(256, 4)
void k_gemmp(const float* __restrict__ x, const ushort_t* __restrict__ wt,
             const int* __restrict__ wsCnt, const int* __restrict__ wsList,
             const float4* __restrict__ selW, const float* __restrict__ wsBet,
             float* __restrict__ out) {
    int bx = blockIdx.x;
    int ct = bx & 7;                   // col slab: ct*64..+64
    int bt = bx >> 3;                  // global row-tile index

    // map bt -> (pair li, local tile lt) via 64-entry prefix scan
    int li = -1, lt = 0, cntE = 0, run = 0;
    #pragma unroll 1
    for (int i = 0; i < 64; ++i) {
        int ci = wsCnt[i * 16];
        int ti = (ci + 63) >> 6;
        if (li < 0 && bt < run + ti) { li = i; lt = bt - run; cntE = ci; }
        run += ti;
    }
    if (li < 0) return;                // surplus block
    int e0 = li >> 3, e1 = li & 7;
    const int* listE = wsList + (size_t)li * N_TOK;

    __shared__ ushort_t Blds[2][2][64 * 64];   // [buf][expert], 32 KB total

    int tid = threadIdx.x;
    int wid = tid >> 6, lane = tid & 63;
    int wm = wid * 16;                 // wave's 16-row slice
    int mrow = lane & 15, laneq = lane >> 4, q8 = laneq * 8, qr = laneq * 4;

    // gathered A row + per-expert combine weights for this lane's row
    int idx = lt * 64 + wm + mrow;
    int tok = 0; float w0 = 0.f, w1 = 0.f;
    if (idx < cntE) {
        tok = listE[idx];
        float4 w4 = selW[tok];
        w0 = w4.x; w1 = w4.y;          // rw*gam per expert
    }
    const float* arowp = x + (size_t)tok * INL + q8;

    // B staging (per expert panel, proven rotate swizzle):
    // chunk c -> col=c>>3, kslot=c&7, src kgrp=(kslot-col)&7
    // c1 = c0+256: col1=col0+32, kg1=kg0 -> global off = +32*INL, lds off = +2048
    int c0 = tid;
    int col0 = c0 >> 3, kg0 = ((c0 & 7) - col0) & 7;
    const ushort_t* pB = wt + (size_t)e0 * EOFF + (size_t)(ct * 64 + col0) * INL + kg0 * 8;
    ptrdiff_t dE = (ptrdiff_t)(e1 - e0) * EOFF;
    ushort_t* ldsA = &Blds[0][0][0] + wid * 512;   // wave-uniform chunk region

    // fragment read swizzle
    int fcol[4], frot0[4];
    for (int nt = 0; nt < 4; ++nt) {
        fcol[nt] = nt * 16 + mrow;
        frot0[nt] = (laneq + fcol[nt]) & 7;
    }

    floatx4 comb[4];
    for (int nt = 0; nt < 4; ++nt) comb[nt] = (floatx4){0.f, 0.f, 0.f, 0.f};

    // prologue: DMA kc=0 (both experts) into buf0, drain
    dma16(pB,                ldsA);
    dma16(pB + 32 * INL,     ldsA + 2048);
    dma16(pB + dE,           ldsA + 4096);
    dma16(pB + dE + 32 * INL, ldsA + 6144);
    __syncthreads();

    #pragma unroll 1
    for (int kc = 0; kc < 8; ++kc) {
        int buf = kc & 1;
        // issue DMA for next kc (both experts) into the other buffer
        if (kc < 7) {
            const ushort_t* p = pB + (kc + 1) * 64;
            ushort_t* l = ldsA + (buf ^ 1) * 8192;
            dma16(p,                 l);
            dma16(p + 32 * INL,      l + 2048);
            dma16(p + dE,            l + 4096);
            dma16(p + dE + 32 * INL, l + 6144);
        }

        // A row fp32 loads for this kc
        const float* ap = arowp + kc * 64;
        float4 a00 = *(const float4*)(ap);
        float4 a01 = *(const float4*)(ap + 4);
        float4 a10 = *(const float4*)(ap + 32);
        float4 a11 = *(const float4*)(ap + 36);

        const ushort_t* Bb = &Blds[buf][0][0];
        #pragma unroll
        for (int e = 0; e < 2; ++e) {
            float wv = e ? w1 : w0;
            union AF { uint4 u; short8 s; } af[2];
            af[0].u.x = pkbf(a00.x * wv, a00.y * wv);
            af[0].u.y = pkbf(a00.z * wv, a00.w * wv);
            af[0].u.z = pkbf(a01.x * wv, a01.y * wv);
            af[0].u.w = pkbf(a01.z * wv, a01.w * wv);
            af[1].u.x = pkbf(a10.x * wv, a10.y * wv);
            af[1].u.y = pkbf(a10.z * wv, a10.w * wv);
            af[1].u.z = pkbf(a11.x * wv, a11.y * wv);
            af[1].u.w = pkbf(a11.z * wv, a11.w * wv);

            const ushort_t* B = Bb + e * 4096;
            short8 bf[4][2];
            #pragma unroll
            for (int nt = 0; nt < 4; ++nt) {
                int cb = fcol[nt] * 64;
                bf[nt][0] = *(const short8*)&B[cb + frot0[nt] * 8];
                bf[nt][1] = *(const short8*)&B[cb + ((frot0[nt] + 4) & 7) * 8];
            }
            #pragma unroll
            for (int ks = 0; ks < 2; ++ks)
                for (int nt = 0; nt < 4; ++nt)
                    comb[nt] = __builtin_amdgcn_mfma_f32_16x16x32_bf16(
                        af[ks].s, bf[nt][ks], comb[nt], 0, 0, 0);
        }
        __syncthreads();   // drain next-DMA (overlapped) + release buf readers
    }

    // epilogue: complete output = comb + rw0*bet_eff[e0] + rw1*bet_eff[e1]
    #pragma unroll
    for (int ri = 0; ri < 4; ++ri) {
        int idx2 = lt * 64 + wm + qr + ri;
        if (idx2 >= cntE) continue;
        int tok2 = listE[idx2];
        float4 w4 = selW[tok2];
        float* op = out + (size_t)tok2 * OUTL + ct * 64;
        #pragma unroll
        for (int nt = 0; nt < 4; ++nt) {
            int col = ct * 64 + nt * 16 + mrow;
            float bet = w4.z * wsBet[e0 * OUTL + col] + w4.w * wsBet[e1 * OUTL + col];
            op[nt * 16 + mrow] = comb[nt][ri] + bet;
        }
    }
}

extern "C" void kernel_launch(void* const* d_in, const int* in_sizes, int n_in,
                              void* d_out, int out_size, void* d_ws, size_t ws_size,
                              hipStream_t stream) {
    const float* x        = (const float*)d_in[0];
    const float* ins      = (const float*)d_in[1];
    const float* gate_w   = (const float*)d_in[2];
    const float* expert_w = (const float*)d_in[3];
    const float* expert_b = (const float*)d_in[4];
    const float* gamma_w  = (const float*)d_in[5];
    const float* beta_w   = (const float*)d_in[6];
    const float* rmod_w   = (const float*)d_in[7];
    float* out = (float*)d_out;

    char* ws = (char*)d_ws;
    int*      wsCnt  = (int*)(ws + WS_CNT);
    float*    wsGam  = (float*)(ws + WS_GAM);
    float*    wsRgam = (float*)(ws + WS_RGAM);
    float*    wsBet  = (float*)(ws + WS_BET);
    float4*   selW   = (float4*)(ws + WS_SELW);
    ushort_t* wt     = (ushort_t*)(ws + WS_WT);
    int*      wsList = (int*)(ws + WS_LIST);

    k_prep<<<641, 256, 0, stream>>>(ins, expert_w, expert_b,
                                    gamma_w, beta_w, rmod_w,
                                    wt, wsBet, wsGam, wsRgam, wsCnt);
    k_route<<<N_TOK / 16, 256, 0, stream>>>(x, gate_w, wsGam, wsRgam,
                                            selW, wsCnt, wsList);
    k_gemmp<<<MAXTP * 8, 256, 0, stream>>>(x, wt, wsCnt, wsList,
                                           selW, wsBet, out);
}

// Round 5
// 139.689 us; speedup vs baseline: 1.5304x; 1.1861x over previous
//
#include <hip/hip_runtime.h>
#include <hip/hip_bf16.h>

// Problem constants
#define N_TOK 8192
#define INL   512
#define OUTL  512
#define NE    8
#define NI    16
#define EOFF  (OUTL * INL)   // elems per expert in wt

typedef unsigned short ushort_t;
typedef unsigned int   uint_t;
typedef short  short8  __attribute__((ext_vector_type(8)));
typedef float  floatx4 __attribute__((ext_vector_type(4)));

// ---------------- workspace layout (bytes) ----------------
#define WS_CNT    0u         // int[64] @ stride 16 ints (64B): pair = e0*8+e1
#define WS_GAM    4096u      // float[8]   : gam[e]
#define WS_RGAM   4352u      // float[8]   : router_gamma[e]
#define WS_SCHED  4608u      // int[184]   : packed tile schedule
#define WS_BET    8192u      // float[4096]: bet_eff[e][d] = bet + gam*b
#define WS_SELW   32768u     // float4[8192]: {rw0*gam0, rw1*gam1, rw0, rw1}
#define WS_WT     163840u    // ushort[8*512*512] : W^T bf16 [e][d][l]
#define WS_LIST   4358144u   // int[64*8192] : token lists per pair
#define MAXTP     184        // bound: 56 pairs + 8192/64 tiles

__device__ __forceinline__ ushort_t f2bf(float f) {
    uint_t b = __float_as_uint(f);
    return (ushort_t)((b + 0x7FFFu + ((b >> 16) & 1u)) >> 16);   // RNE
}
__device__ __forceinline__ uint_t pkbf(float a, float b) {
    __hip_bfloat162 h = __float22bfloat162_rn(make_float2(a, b));  // v_cvt_pk_bf16_f32
    union { __hip_bfloat162 h2; uint_t u; } cv;
    cv.h2 = h;
    return cv.u;
}
// async global->LDS DMA, 16 B per lane; LDS dest = wave-uniform base + lane*16
__device__ __forceinline__ void dma16(const ushort_t* g, ushort_t* l) {
    __builtin_amdgcn_global_load_lds(
        (const __attribute__((address_space(1))) void*)g,
        (__attribute__((address_space(3))) void*)l,
        16, 0, 0);
}

// ================= K1: fused prep =================
// blocks [0,512):   Wt transpose/convert  (e = bx>>6; tile = bx&63)
// blocks [512,640): bet_eff               (e = b>>4; dBase = (b&15)*32)
// block  640:       stats -> wsGam, wsRgam; zero pair counters
__global__ __launch_bounds__(256)
void k_prep(const float* __restrict__ ins,
            const float* __restrict__ expert_w,
            const float* __restrict__ expert_b,
            const float* __restrict__ gamma_w,
            const float* __restrict__ beta_w,
            const float* __restrict__ rmod_w,
            ushort_t* __restrict__ wt,
            float* __restrict__ wsBet,
            float* __restrict__ wsGam, float* __restrict__ wsRgam,
            int* __restrict__ wsCnt) {
    __shared__ __align__(16) char smem[17152];
    int bx = blockIdx.x;
    int tid = threadIdx.x;

    if (bx < 512) {
        float (*tile)[65] = (float(*)[65])smem;
        int e = bx >> 6, rem = bx & 63;
        int lt = (rem >> 3) * 64, dt = (rem & 7) * 64;
        int dIdx = tid & 63, lq = tid >> 6;
        for (int i = 0; i < 16; ++i) {
            int l = lq * 16 + i;
            tile[l][dIdx] = expert_w[(e * INL + lt + l) * OUTL + dt + dIdx];
        }
        __syncthreads();
        int lIdx = tid & 63, dq = tid >> 6;
        for (int i = 0; i < 16; ++i) {
            int d = dq * 16 + i;
            wt[(e * OUTL + dt + d) * INL + lt + lIdx] = f2bf(tile[lIdx][d]);
        }
        return;
    }

    if (bx < 640) {
        float* sS  = (float*)smem;          // [512]
        float* red = sS + 512;              // [256]
        float* gamS = red + 256;            // [1]
        int b2 = bx - 512;
        int e = b2 >> 4, dBase = (b2 & 15) * 32;
        for (int h = tid; h < INL; h += 256) {
            float a = 0.f;
            for (int n = 0; n < NI; ++n) a += ins[n * INL + h];
            sS[h] = a;
        }
        __syncthreads();
        if (tid < 64) {
            float g = 0.f;
            for (int j = 0; j < 8; ++j) g += sS[tid * 8 + j] * gamma_w[e * INL + tid * 8 + j];
            for (int off = 32; off >= 1; off >>= 1) g += __shfl_xor(g, off, 64);
            if (tid == 0) gamS[0] = g * (1.f / NI);
        }
        int doff = tid & 31, hq = tid >> 5;
        float a = 0.f;
        for (int j = 0; j < 64; ++j) {
            int h = hq * 64 + j;
            a += sS[h] * beta_w[(e * INL + h) * OUTL + dBase + doff];
        }
        red[tid] = a;
        __syncthreads();
        if (tid < 32) {
            float t = 0.f;
            for (int k = 0; k < 8; ++k) t += red[k * 32 + tid];
            int d = dBase + tid;
            wsBet[e * OUTL + d] = t * (1.f / NI) + gamS[0] * expert_b[e * OUTL + d];
        }
        return;
    }

    {   // stats
        if (tid < 64) wsCnt[tid * 16] = 0;   // zero pair counters for k_route
        float* sS = (float*)smem;           // [512]
        float* pg = sS + 512;               // [64]
        float* pr = pg + 64;                // [64]
        for (int h = tid; h < INL; h += 256) {
            float a = 0.f;
            for (int n = 0; n < NI; ++n) a += ins[n * INL + h];
            sS[h] = a;
        }
        __syncthreads();
        if (tid < 64) {
            int e = tid & 7, qq = tid >> 3;
            float g = 0.f, r = 0.f;
            for (int j = 0; j < 64; ++j) {
                int h = qq * 64 + j;
                float sv = sS[h];
                g += sv * gamma_w[e * INL + h];
                r += sv * rmod_w[h * NE + e];
            }
            pg[tid] = g; pr[tid] = r;
        }
        __syncthreads();
        if (tid < NE) {
            float g = 0.f, r = 0.f;
            for (int qq = 0; qq < 8; ++qq) { g += pg[qq * 8 + tid]; r += pr[qq * 8 + tid]; }
            wsGam[tid]  = g * (1.f / NI);
            wsRgam[tid] = r * (1.f / NI);
        }
    }
}

// ================= K2: router + pair scatter (512 blocks, 16 tok/block) ====
// Routing math = round-0 proven structure (high occupancy, 4 serial tok/wave).
// Scatter: 64-bin LDS pair histogram, <=16 global atomicAdds per block onto
// 64B-padded counters, then compacted list writes. No out writes here.
__global__ __launch_bounds__(256)
void k_route(const float* __restrict__ x,
             const float* __restrict__ gate_w,
             const float* __restrict__ wsGam,
             const float* __restrict__ wsRgam,
             float4* __restrict__ selW,
             int* __restrict__ wsCnt, int* __restrict__ wsList) {
    __shared__ float gateT[NE * INL];   // 16 KB, [e][l]
    __shared__ int tokP[16];
    __shared__ int cnt64[64], base64[64], pos[16];

    int tid = threadIdx.x;
    for (int i = 0; i < 16; ++i) {
        int f = tid + 256 * i;
        gateT[(f & 7) * INL + (f >> 3)] = gate_w[f];
    }
    if (tid < 64) cnt64[tid] = 0;
    __syncthreads();

    int w = tid >> 6, lane = tid & 63;
    int tbase = blockIdx.x * 16 + w * 4;

    for (int tt = 0; tt < 4; ++tt) {
        int t = tbase + tt;
        float2 xv[4];
        for (int i = 0; i < 4; ++i)
            xv[i] = *(const float2*)(x + (size_t)t * INL + 2 * lane + 128 * i);

        float acc[NE];
        for (int e = 0; e < NE; ++e) acc[e] = 0.f;
        for (int i = 0; i < 4; ++i) {
            int c = 2 * lane + 128 * i;
            for (int e = 0; e < NE; ++e)
                acc[e] += xv[i].x * gateT[e * INL + c] + xv[i].y * gateT[e * INL + c + 1];
        }
        for (int e = 0; e < NE; ++e) {
            float a = acc[e];
            for (int off = 32; off >= 1; off >>= 1) a += __shfl_xor(a, off, 64);
            acc[e] = a;
        }
        float logit[NE];
        for (int e = 0; e < NE; ++e) logit[e] = acc[e] + wsRgam[e];

        int i0 = 0; float m0 = logit[0];
        for (int e = 1; e < NE; ++e) if (logit[e] > m0) { m0 = logit[e]; i0 = e; }
        int i1 = -1; float m1 = -3.4e38f;
        for (int e = 0; e < NE; ++e) if (e != i0 && logit[e] > m1) { m1 = logit[e]; i1 = e; }

        float S = 0.f;
        for (int e = 0; e < NE; ++e) S += expf(logit[e] - m0);
        float rw0 = 1.0f / S;
        float rw1 = expf(m1 - m0) / S;

        if (lane == 0) {
            selW[t] = make_float4(rw0 * wsGam[i0], rw1 * wsGam[i1], rw0, rw1);
            tokP[w * 4 + tt] = i0 * 8 + i1;
        }
    }
    __syncthreads();

    if (tid < 16) pos[tid] = atomicAdd(&cnt64[tokP[tid]], 1);
    __syncthreads();
    if (tid < 64 && cnt64[tid] > 0)
        base64[tid] = atomicAdd(wsCnt + tid * 16, cnt64[tid]);
    __syncthreads();
    if (tid < 16) {
        int p = tokP[tid];
        wsList[(size_t)p * N_TOK + base64[p] + pos[tid]] = blockIdx.x * 16 + tid;
    }
}

// ================= K2b: build packed tile schedule (1 block) ===============
// sched[j] = li | (lt << 6) | (cnt << 14); tail = -1. Replaces the per-block
// 64-load serial prefix scan in the gemm (the round-4 latency killer).
__global__ __launch_bounds__(256)
void k_sched(const int* __restrict__ wsCnt, int* __restrict__ sched) {
    __shared__ int cnt[64], base[64], totS;
    int tid = threadIdx.x;
    if (tid < 64) cnt[tid] = wsCnt[tid * 16];
    __syncthreads();
    if (tid == 0) {
        int run = 0;
        for (int i = 0; i < 64; ++i) {
            base[i] = run;
            run += (cnt[i] + 63) >> 6;
        }
        totS = run;
    }
    __syncthreads();
    if (tid < 64) {
        int c = cnt[tid], ti = (c + 63) >> 6, b = base[tid];
        for (int j = 0; j < ti; ++j)
            sched[b + j] = tid | (j << 6) | (c << 14);
    }
    for (int j = totS + tid; j < MAXTP; j += 256)
        sched[j] = -1;
}

// ================= K3: pair-gather GEMM, single pass, no atomics ===========
// Block owns (pair (e0,e1), 64-token tile, 64-col slab). One packed sched
// load replaces the 64-load scan. A fragments for kc+1 are prefetched into
// registers alongside the kc+1 DMA (the barrier's vmcnt(0) completes both),
// so each kc's pack starts stall-free.
__global__ __launch_bounds__(256, 4)
void k_gemmp(const float* __restrict__ x, const ushort_t* __restrict__ wt,
             const int* __restrict__ sched, const int* __restrict__ wsList,
             const float4* __restrict__ selW, const float* __restrict__ wsBet,
             float* __restrict__ out) {
    int bx = blockIdx.x;
    int ct = bx & 7;                   // col slab: ct*64..+64
    int bt = bx >> 3;                  // global row-tile index

    int s = sched[bt];
    if (s < 0) return;                 // surplus block
    int li = s & 63, lt = (s >> 6) & 127, cntE = s >> 14;
    int e0 = li >> 3, e1 = li & 7;
    const int* listE = wsList + (size_t)li * N_TOK;

    __shared__ ushort_t Blds[2][2][64 * 64];   // [buf][expert], 32 KB total

    int tid = threadIdx.x;
    int wid = tid >> 6, lane = tid & 63;
    int wm = wid * 16;                 // wave's 16-row slice
    int mrow = lane & 15, laneq = lane >> 4, q8 = laneq * 8, qr = laneq * 4;

    // gathered A row + per-expert combine weights for this lane's row
    int idx = lt * 64 + wm + mrow;
    int tok = 0; float w0 = 0.f, w1 = 0.f;
    if (idx < cntE) {
        tok = listE[idx];
        float4 w4 = selW[tok];
        w0 = w4.x; w1 = w4.y;          // rw*gam per expert
    }
    const float* arowp = x + (size_t)tok * INL + q8;

    // B staging (per expert panel, proven rotate swizzle):
    // chunk c -> col=c>>3, kslot=c&7, src kgrp=(kslot-col)&7
    // c1 = c0+256: col1=col0+32, kg1=kg0 -> global off = +32*INL, lds off = +2048
    int c0 = tid;
    int col0 = c0 >> 3, kg0 = ((c0 & 7) - col0) & 7;
    const ushort_t* pB = wt + (size_t)e0 * EOFF + (size_t)(ct * 64 + col0) * INL + kg0 * 8;
    ptrdiff_t dE = (ptrdiff_t)(e1 - e0) * EOFF;
    ushort_t* ldsA = &Blds[0][0][0] + wid * 512;   // wave-uniform chunk region

    // fragment read swizzle
    int fcol[4], frot0[4];
    for (int nt = 0; nt < 4; ++nt) {
        fcol[nt] = nt * 16 + mrow;
        frot0[nt] = (laneq + fcol[nt]) & 7;
    }

    floatx4 comb[4];
    for (int nt = 0; nt < 4; ++nt) comb[nt] = (floatx4){0.f, 0.f, 0.f, 0.f};

    // prologue: DMA kc=0 (both experts) into buf0 + A regs for kc=0, drain
    dma16(pB,                 ldsA);
    dma16(pB + 32 * INL,      ldsA + 2048);
    dma16(pB + dE,            ldsA + 4096);
    dma16(pB + dE + 32 * INL, ldsA + 6144);
    float4 a00 = *(const float4*)(arowp);
    float4 a01 = *(const float4*)(arowp + 4);
    float4 a10 = *(const float4*)(arowp + 32);
    float4 a11 = *(const float4*)(arowp + 36);
    __syncthreads();

    #pragma unroll
    for (int kc = 0; kc < 8; ++kc) {
        int buf = kc & 1;
        float4 n00, n01, n10, n11;
        // issue DMA + A-reg prefetch for next kc (both fly under this kc's
        // compute; the end-of-kc barrier's vmcnt(0) completes them)
        if (kc < 7) {
            const ushort_t* p = pB + (kc + 1) * 64;
            ushort_t* l = ldsA + (buf ^ 1) * 8192;
            dma16(p,                 l);
            dma16(p + 32 * INL,      l + 2048);
            dma16(p + dE,            l + 4096);
            dma16(p + dE + 32 * INL, l + 6144);
            const float* ap = arowp + (kc + 1) * 64;
            n00 = *(const float4*)(ap);
            n01 = *(const float4*)(ap + 4);
            n10 = *(const float4*)(ap + 32);
            n11 = *(const float4*)(ap + 36);
        }

        const ushort_t* Bb = &Blds[buf][0][0];
        #pragma unroll
        for (int e = 0; e < 2; ++e) {
            float wv = e ? w1 : w0;
            union AF { uint4 u; short8 s; } af[2];
            af[0].u.x = pkbf(a00.x * wv, a00.y * wv);
            af[0].u.y = pkbf(a00.z * wv, a00.w * wv);
            af[0].u.z = pkbf(a01.x * wv, a01.y * wv);
            af[0].u.w = pkbf(a01.z * wv, a01.w * wv);
            af[1].u.x = pkbf(a10.x * wv, a10.y * wv);
            af[1].u.y = pkbf(a10.z * wv, a10.w * wv);
            af[1].u.z = pkbf(a11.x * wv, a11.y * wv);
            af[1].u.w = pkbf(a11.z * wv, a11.w * wv);

            const ushort_t* B = Bb + e * 4096;
            short8 bf[4][2];
            #pragma unroll
            for (int nt = 0; nt < 4; ++nt) {
                int cb = fcol[nt] * 64;
                bf[nt][0] = *(const short8*)&B[cb + frot0[nt] * 8];
                bf[nt][1] = *(const short8*)&B[cb + ((frot0[nt] + 4) & 7) * 8];
            }
            #pragma unroll
            for (int ks = 0; ks < 2; ++ks)
                for (int nt = 0; nt < 4; ++nt)
                    comb[nt] = __builtin_amdgcn_mfma_f32_16x16x32_bf16(
                        af[ks].s, bf[nt][ks], comb[nt], 0, 0, 0);
        }
        __syncthreads();   // drain next-DMA + A prefetch, release buf readers
        if (kc < 7) { a00 = n00; a01 = n01; a10 = n10; a11 = n11; }
    }

    // epilogue: complete output = comb + rw0*bet_eff[e0] + rw1*bet_eff[e1]
    #pragma unroll
    for (int ri = 0; ri < 4; ++ri) {
        int idx2 = lt * 64 + wm + qr + ri;
        if (idx2 >= cntE) continue;
        int tok2 = listE[idx2];
        float4 w4 = selW[tok2];
        float* op = out + (size_t)tok2 * OUTL + ct * 64;
        #pragma unroll
        for (int nt = 0; nt < 4; ++nt) {
            int col = ct * 64 + nt * 16 + mrow;
            float bet = w4.z * wsBet[e0 * OUTL + col] + w4.w * wsBet[e1 * OUTL + col];
            op[nt * 16 + mrow] = comb[nt][ri] + bet;
        }
    }
}

extern "C" void kernel_launch(void* const* d_in, const int* in_sizes, int n_in,
                              void* d_out, int out_size, void* d_ws, size_t ws_size,
                              hipStream_t stream) {
    const float* x        = (const float*)d_in[0];
    const float* ins      = (const float*)d_in[1];
    const float* gate_w   = (const float*)d_in[2];
    const float* expert_w = (const float*)d_in[3];
    const float* expert_b = (const float*)d_in[4];
    const float* gamma_w  = (const float*)d_in[5];
    const float* beta_w   = (const float*)d_in[6];
    const float* rmod_w   = (const float*)d_in[7];
    float* out = (float*)d_out;

    char* ws = (char*)d_ws;
    int*      wsCnt  = (int*)(ws + WS_CNT);
    float*    wsGam  = (float*)(ws + WS_GAM);
    float*    wsRgam = (float*)(ws + WS_RGAM);
    int*      wsSch  = (int*)(ws + WS_SCHED);
    float*    wsBet  = (float*)(ws + WS_BET);
    float4*   selW   = (float4*)(ws + WS_SELW);
    ushort_t* wt     = (ushort_t*)(ws + WS_WT);
    int*      wsList = (int*)(ws + WS_LIST);

    k_prep<<<641, 256, 0, stream>>>(ins, expert_w, expert_b,
                                    gamma_w, beta_w, rmod_w,
                                    wt, wsBet, wsGam, wsRgam, wsCnt);
    k_route<<<N_TOK / 16, 256, 0, stream>>>(x, gate_w, wsGam, wsRgam,
                                            selW, wsCnt, wsList);
    k_sched<<<1, 256, 0, stream>>>(wsCnt, wsSch);
    k_gemmp<<<MAXTP * 8, 256, 0, stream>>>(x, wt, wsSch, wsList,
                                           selW, wsBet, out);
}